// Round 2
// baseline (4515.844 us; speedup 1.0000x reference)
//
#include <hip/hip_runtime.h>

// ---------------------------------------------------------------------------
// Round 6: kill the serial softmax + hide staging latency.
//   attn4 changes vs round 5:
//   - phase 1: split-stage (global->reg before compute, ds_write after),
//     rows padded to 52 so the 13-row register tile has no predicate.
//   - phases 2-4: per head, lane j keeps k[j][0:32] in registers; each wave
//     owns rows i = wv,wv+4,...  S computed per-lane (q broadcast from LDS,
//     bias gathered straight from bt), softmax via 6-step shfl_xor
//     butterflies, P written to S_s once. 2 barriers/head (was 4).
//     q slice double-buffered across heads.
//   proj32 unchanged except a mild unroll hint.
// All math fp32.
// ---------------------------------------------------------------------------

#define FMA4(accv, f, w0, w1, w2, w3)                                          \
  accv.x = fmaf(f.x, w0.x, accv.x); accv.x = fmaf(f.y, w1.x, accv.x);          \
  accv.x = fmaf(f.z, w2.x, accv.x); accv.x = fmaf(f.w, w3.x, accv.x);          \
  accv.y = fmaf(f.x, w0.y, accv.y); accv.y = fmaf(f.y, w1.y, accv.y);          \
  accv.y = fmaf(f.z, w2.y, accv.y); accv.y = fmaf(f.w, w3.y, accv.y);          \
  accv.z = fmaf(f.x, w0.z, accv.z); accv.z = fmaf(f.y, w1.z, accv.z);          \
  accv.z = fmaf(f.z, w2.z, accv.z); accv.z = fmaf(f.w, w3.z, accv.z);          \
  accv.w = fmaf(f.x, w0.w, accv.w); accv.w = fmaf(f.y, w1.w, accv.w);          \
  accv.w = fmaf(f.z, w2.w, accv.w); accv.w = fmaf(f.w, w3.w, accv.w);

__global__ __launch_bounds__(256) void attn4(
    const float* __restrict__ inp, const float* __restrict__ qg,
    const float* __restrict__ W, const float* __restrict__ b,
    const float* __restrict__ bt, float* __restrict__ out) {
    __shared__ float kv_s[52][260];     // 54080 B; rows 49-51 are scratch
    __shared__ float S_s[49][53];       // 10388 B; holds P per head
    __shared__ float inp_s[2][52][32];  // 13312 B; staging chunks / q slices

    const int win = blockIdx.x;   // 0..1023
    const int hg  = blockIdx.y;   // head group 0..3
    const int t   = threadIdx.x;  // 0..255
    const int c4  = t & 63;       // float4 column 0..63
    const int rg  = t >> 6;       // row group / wave id 0..3
    const int wv  = rg;
    const int j   = c4;           // lane id within wave

    const int colbase = (c4 < 32) ? (hg * 128 + (c4 << 2))
                                  : (512 + hg * 128 + ((c4 - 32) << 2));
    const float* ip = inp + (size_t)win * 49 * 512;

    // cooperative-staging indices (49x32 chunk = 392 float4, 256 threads)
    const int sr0 = t >> 3, sc0 = (t & 7) << 2;
    const int sr1 = (t + 256) >> 3, sc1 = ((t + 256) & 7) << 2;
    const bool has2 = (t < 136);

    // ---- phase 1: kv tile = inp[win] @ W[:, cols] + b --------------------
    float4 acc[13];
#pragma unroll
    for (int rr = 0; rr < 13; ++rr) acc[rr] = make_float4(0.f, 0.f, 0.f, 0.f);
    const float4 bias4 = *(const float4*)(b + colbase);

    // prologue: chunk 0
    *(float4*)&inp_s[0][sr0][sc0] = *(const float4*)(ip + (size_t)sr0 * 512 + sc0);
    if (has2)
        *(float4*)&inp_s[0][sr1][sc1] = *(const float4*)(ip + (size_t)sr1 * 512 + sc1);
    __syncthreads();

    for (int kc = 0; kc < 512; kc += 32) {
        const int cur = (kc >> 5) & 1;
        const bool more = (kc + 32 < 512);
        float4 st0, st1;
        if (more) {  // issue next-chunk loads BEFORE compute (latency hidden)
            const float* src = ip + kc + 32;
            st0 = *(const float4*)(src + (size_t)sr0 * 512 + sc0);
            if (has2) st1 = *(const float4*)(src + (size_t)sr1 * 512 + sc1);
        }
        const float* Wp = W + ((size_t)kc << 10) + colbase;
#pragma unroll
        for (int k4 = 0; k4 < 8; ++k4) {
            const float* wr = Wp + ((size_t)(k4 << 2) << 10);
            float4 w0 = *(const float4*)(wr);
            float4 w1 = *(const float4*)(wr + 1024);
            float4 w2 = *(const float4*)(wr + 2048);
            float4 w3 = *(const float4*)(wr + 3072);
#pragma unroll
            for (int rr = 0; rr < 13; ++rr) {  // rows rg+4*rr < 52, no predicate
                float4 f = *(const float4*)&inp_s[cur][rg + (rr << 2)][k4 << 2];
                FMA4(acc[rr], f, w0, w1, w2, w3)
            }
        }
        if (more) {  // write next chunk AFTER compute
            *(float4*)&inp_s[cur ^ 1][sr0][sc0] = st0;
            if (has2) *(float4*)&inp_s[cur ^ 1][sr1][sc1] = st1;
        }
        __syncthreads();
    }

    // writeback kv tile (+bias); rows 49-51 are garbage, never read
#pragma unroll
    for (int rr = 0; rr < 13; ++rr) {
        const int r = rg + (rr << 2);
        float4 res = make_float4(acc[rr].x + bias4.x, acc[rr].y + bias4.y,
                                 acc[rr].z + bias4.z, acc[rr].w + bias4.w);
        *(float4*)&kv_s[r][c4 << 2] = res;
    }

    // stage q for head 0 into inp_s[0]
    const float* qwin = qg + (size_t)(win >> 4) * 49 * 512 + hg * 128;
    *(float4*)&inp_s[0][sr0][sc0] = *(const float4*)(qwin + (size_t)sr0 * 512 + sc0);
    if (has2)
        *(float4*)&inp_s[0][sr1][sc1] = *(const float4*)(qwin + (size_t)sr1 * 512 + sc1);
    __syncthreads();

    // ---- phases 2-4 per head --------------------------------------------
    // lane constants for bias gather: idx = r_i - c_j, both in [0,168]
    const int jj = (j < 49) ? j : 48;          // clamp pad lanes
    const int jh = jj / 7, jw = jj - jh * 7;
    const int c_j = jh * 13 + jw;

    for (int hh = 0; hh < 4; ++hh) {
        const int H  = (hg << 2) + hh;
        const int qb = hh & 1;

        // prefetch next head's q slice into the other buffer
        if (hh < 3) {
            const float* qn = qwin + ((hh + 1) << 5);
            *(float4*)&inp_s[qb ^ 1][sr0][sc0] =
                *(const float4*)(qn + (size_t)sr0 * 512 + sc0);
            if (has2)
                *(float4*)&inp_s[qb ^ 1][sr1][sc1] =
                    *(const float4*)(qn + (size_t)sr1 * 512 + sc1);
        }

        // lane j holds k[jj][0:32] in registers
        float4 kreg[8];
#pragma unroll
        for (int d4 = 0; d4 < 8; ++d4)
            kreg[d4] = *(const float4*)&kv_s[jj][(hh << 5) + (d4 << 2)];

        // each wave owns rows i = wv, wv+4, ...
        for (int i = wv; i < 49; i += 4) {
            const int ih = i / 7, iw = i - ih * 7;
            const int r_i = ih * 13 + iw + 84;
            float s = 0.f;
#pragma unroll
            for (int d4 = 0; d4 < 8; ++d4) {
                float4 qv = *(const float4*)&inp_s[qb][i][d4 << 2];  // broadcast
                s = fmaf(qv.x, kreg[d4].x, s); s = fmaf(qv.y, kreg[d4].y, s);
                s = fmaf(qv.z, kreg[d4].z, s); s = fmaf(qv.w, kreg[d4].w, s);
            }
            s = s * 0.17677669529663687f + bt[(r_i - c_j) * 16 + H];
            if (j >= 49) s = -1e30f;
            float mx = s;
#pragma unroll
            for (int m = 32; m; m >>= 1) mx = fmaxf(mx, __shfl_xor(mx, m));
            float e = __expf(s - mx);
            float sum = e;
#pragma unroll
            for (int m = 32; m; m >>= 1) sum += __shfl_xor(sum, m);
            float p = e * (1.f / sum);
            if (j < 49) S_s[i][j] = p;
        }
        __syncthreads();

        // PV: X[i][d] = sum_j P[i][j] * v[j][d]
        for (int o = t; o < 392; o += 256) {
            int i = o >> 3, dd = (o & 7) << 2;
            float4 a4 = make_float4(0.f, 0.f, 0.f, 0.f);
#pragma unroll 7
            for (int jq = 0; jq < 49; ++jq) {
                float p = S_s[i][jq];
                float4 vf = *(const float4*)&kv_s[jq][128 + (hh << 5) + dd];
                a4.x = fmaf(p, vf.x, a4.x); a4.y = fmaf(p, vf.y, a4.y);
                a4.z = fmaf(p, vf.z, a4.z); a4.w = fmaf(p, vf.w, a4.w);
            }
            *(float4*)(out + ((size_t)win * 49 + i) * 512 + (H << 5) + dd) = a4;
        }
        __syncthreads();
    }
}

// Kernel 2: in-place out = out @ proj_w + proj_b. 32 rows/block, 16x4 fp32
// register tile per thread. Race-free (each block owns its rows).
__global__ __launch_bounds__(256) void proj32(
    const float* __restrict__ pw, const float* __restrict__ pb,
    float* __restrict__ io) {
    __shared__ float X_s[32][516];  // 66048 B
    const int m0 = blockIdx.x << 5;
    const int t  = threadIdx.x;
    const int c4 = (t & 127) << 2;
    const int rg = t >> 7;

    for (int o = t; o < 4096; o += 256) {
        int r = o >> 7, cc = (o & 127) << 2;
        *(float4*)&X_s[r][cc] =
            *(const float4*)(io + ((size_t)(m0 + r)) * 512 + cc);
    }
    __syncthreads();

    const float4 bias = *(const float4*)(pb + c4);
    float4 acc[16];
#pragma unroll
    for (int r = 0; r < 16; ++r) acc[r] = bias;

    const float* wp = pw + c4;
#pragma unroll 2
    for (int k4 = 0; k4 < 128; ++k4) {
        const float* wr = wp + ((size_t)(k4 << 2) << 9);
        float4 w0 = *(const float4*)(wr);
        float4 w1 = *(const float4*)(wr + 512);
        float4 w2 = *(const float4*)(wr + 1024);
        float4 w3 = *(const float4*)(wr + 1536);
#pragma unroll
        for (int r = 0; r < 16; ++r) {
            float4 f = *(const float4*)&X_s[(rg << 4) + r][k4 << 2];
            FMA4(acc[r], f, w0, w1, w2, w3)
        }
    }

#pragma unroll
    for (int r = 0; r < 16; ++r)
        *(float4*)(io + ((size_t)(m0 + (rg << 4) + r)) * 512 + c4) = acc[r];
}

// ---------------------------------------------------------------------------
extern "C" void kernel_launch(void* const* d_in, const int* in_sizes, int n_in,
                              void* d_out, int out_size, void* d_ws, size_t ws_size,
                              hipStream_t stream) {
    const float* inputs = (const float*)d_in[0];   // [1024*49, 512]
    const float* qg     = (const float*)d_in[1];   // [64*49, 512]
    const float* qkv_w  = (const float*)d_in[2];   // [512, 1024]
    const float* qkv_b  = (const float*)d_in[3];   // [1024]
    const float* btab   = (const float*)d_in[4];   // [169, 16]
    const float* proj_w = (const float*)d_in[5];   // [512, 512]
    const float* proj_b = (const float*)d_in[6];   // [512]
    float* out = (float*)d_out;                    // [1024*49, 512]
    (void)d_ws; (void)ws_size;

    attn4<<<dim3(1024, 4), 256, 0, stream>>>(inputs, qg, qkv_w, qkv_b, btab, out);
    proj32<<<50176 / 32, 256, 0, stream>>>(proj_w, proj_b, out);
}

// Round 3
// 2145.746 us; speedup vs baseline: 2.1046x; 2.1046x over previous
//
#include <hip/hip_runtime.h>

// ---------------------------------------------------------------------------
// Round 7: round-6 structure, but ALL staging via global_load_lds (async
// global->LDS DMA, zero VGPR round-trip). Round 6's register-held staging
// spilled (VGPR cap 256) -> 12 GB scratch traffic. GLL removes the pressure
// while keeping the issue-early/consume-after-barrier pipeline.
//   attn4: phase-1 input chunks + per-head q slices staged with GLL,
//          double-buffered; wave-parallel in-register softmax kept.
//   proj32: X tile staged with GLL (unpadded [32][512], reads are wave-
//          broadcast so banking is irrelevant); 1-deep W register prefetch.
// All math fp32.
// ---------------------------------------------------------------------------

typedef __attribute__((address_space(3))) void lds_void;
typedef const __attribute__((address_space(1))) void glb_void;

// One 16-B async copy: global (per-lane addr) -> LDS (wave-uniform base,
// HW adds lane*16). Size must be a literal.
__device__ __forceinline__ void cp16_async(const float* g, float* lds_wave_base) {
    __builtin_amdgcn_global_load_lds((glb_void*)g, (lds_void*)lds_wave_base, 16, 0, 0);
}

// Stage a 49x32-float tile (source row stride 512 floats) into contiguous
// LDS rows of 32 floats. 392 float4 total; last 8 handled by a partial wave
// (exec-masked lanes issue nothing).
__device__ __forceinline__ void stage49x32(const float* src, float* dst, int t) {
#pragma unroll
    for (int it = 0; it < 2; ++it) {
        const int o = t + (it << 8);        // float4 index
        if (o < 392) {
            const int wb = o & ~63;         // wave-uniform f4 base
            cp16_async(src + (size_t)(o >> 3) * 512 + ((o & 7) << 2),
                       dst + (wb << 2));
        }
    }
}

#define FMA4(accv, f, w0, w1, w2, w3)                                          \
  accv.x = fmaf(f.x, w0.x, accv.x); accv.x = fmaf(f.y, w1.x, accv.x);          \
  accv.x = fmaf(f.z, w2.x, accv.x); accv.x = fmaf(f.w, w3.x, accv.x);          \
  accv.y = fmaf(f.x, w0.y, accv.y); accv.y = fmaf(f.y, w1.y, accv.y);          \
  accv.y = fmaf(f.z, w2.y, accv.y); accv.y = fmaf(f.w, w3.y, accv.y);          \
  accv.z = fmaf(f.x, w0.z, accv.z); accv.z = fmaf(f.y, w1.z, accv.z);          \
  accv.z = fmaf(f.z, w2.z, accv.z); accv.z = fmaf(f.w, w3.z, accv.z);          \
  accv.w = fmaf(f.x, w0.w, accv.w); accv.w = fmaf(f.y, w1.w, accv.w);          \
  accv.w = fmaf(f.z, w2.w, accv.w); accv.w = fmaf(f.w, w3.w, accv.w);

__global__ __launch_bounds__(256) void attn4(
    const float* __restrict__ inp, const float* __restrict__ qg,
    const float* __restrict__ W, const float* __restrict__ b,
    const float* __restrict__ bt, float* __restrict__ out) {
    __shared__ float kv_s[52][260];     // 54080 B; rows 49-51 scratch
    __shared__ float S_s[49][53];       // 10388 B; P per head
    __shared__ float inp_s[2][52][32];  // 13312 B; GLL chunks / q slices
    // total 77780 B -> 2 blocks/CU

    const int win = blockIdx.x;   // 0..1023
    const int hg  = blockIdx.y;   // head group 0..3
    const int t   = threadIdx.x;  // 0..255
    const int c4  = t & 63;       // float4 column / lane id
    const int rg  = t >> 6;       // wave id
    const int j   = c4;

    const int colbase = (c4 < 32) ? (hg * 128 + (c4 << 2))
                                  : (512 + hg * 128 + ((c4 - 32) << 2));
    const float* ip = inp + (size_t)win * 49 * 512;

    // ---- phase 1: kv tile = inp[win] @ W[:, cols] + b --------------------
    float4 acc[13];
#pragma unroll
    for (int rr = 0; rr < 13; ++rr) acc[rr] = make_float4(0.f, 0.f, 0.f, 0.f);
    const float4 bias4 = *(const float4*)(b + colbase);

    stage49x32(ip, &inp_s[0][0][0], t);      // chunk 0 (async)
    __syncthreads();                          // drains vmcnt -> chunk 0 ready

    for (int kc = 0; kc < 512; kc += 32) {
        const int cur = (kc >> 5) & 1;
        if (kc + 32 < 512)                    // issue next chunk BEFORE compute
            stage49x32(ip + kc + 32, &inp_s[cur ^ 1][0][0], t);

        const float* Wp = W + ((size_t)kc << 10) + colbase;
#pragma unroll
        for (int k4 = 0; k4 < 8; ++k4) {
            const float* wr = Wp + ((size_t)(k4 << 2) << 10);
            float4 w0 = *(const float4*)(wr);
            float4 w1 = *(const float4*)(wr + 1024);
            float4 w2 = *(const float4*)(wr + 2048);
            float4 w3 = *(const float4*)(wr + 3072);
#pragma unroll
            for (int rr = 0; rr < 13; ++rr) {   // rows < 52, no predicate
                float4 f = *(const float4*)&inp_s[cur][rg + (rr << 2)][k4 << 2];
                FMA4(acc[rr], f, w0, w1, w2, w3)
            }
        }
        __syncthreads();   // barrier drain lands AFTER ~3.3k cyc of FMA
    }

    // writeback kv tile (+bias); rows 49-51 garbage, never read
#pragma unroll
    for (int rr = 0; rr < 13; ++rr) {
        const int r = rg + (rr << 2);
        float4 res = make_float4(acc[rr].x + bias4.x, acc[rr].y + bias4.y,
                                 acc[rr].z + bias4.z, acc[rr].w + bias4.w);
        *(float4*)&kv_s[r][c4 << 2] = res;
    }

    // stage q for head 0 (async; inp_s[0] last read two barriers ago)
    const float* qwin = qg + (size_t)(win >> 4) * 49 * 512 + hg * 128;
    stage49x32(qwin, &inp_s[0][0][0], t);
    __syncthreads();

    // ---- phases 2-4 per head --------------------------------------------
    const int jj = (j < 49) ? j : 48;          // clamp pad lanes
    const int jh = jj / 7, jw = jj - jh * 7;
    const int c_j = jh * 13 + jw;

    for (int hh = 0; hh < 4; ++hh) {
        const int H  = (hg << 2) + hh;
        const int qb = hh & 1;

        if (hh < 3)   // async prefetch next head's q; lands before next head's barrier
            stage49x32(qwin + ((hh + 1) << 5), &inp_s[qb ^ 1][0][0], t);

        // lane j holds k[jj][0:32] in registers
        float4 kreg[8];
#pragma unroll
        for (int d4 = 0; d4 < 8; ++d4)
            kreg[d4] = *(const float4*)&kv_s[jj][(hh << 5) + (d4 << 2)];

        // each wave owns rows i = wave, wave+4, ...
        for (int i = rg; i < 49; i += 4) {
            const int ih = i / 7, iw = i - ih * 7;
            const int r_i = ih * 13 + iw + 84;
            float s = 0.f;
#pragma unroll
            for (int d4 = 0; d4 < 8; ++d4) {
                float4 qv = *(const float4*)&inp_s[qb][i][d4 << 2];  // broadcast
                s = fmaf(qv.x, kreg[d4].x, s); s = fmaf(qv.y, kreg[d4].y, s);
                s = fmaf(qv.z, kreg[d4].z, s); s = fmaf(qv.w, kreg[d4].w, s);
            }
            s = s * 0.17677669529663687f + bt[(r_i - c_j) * 16 + H];
            if (j >= 49) s = -1e30f;
            float mx = s;
#pragma unroll
            for (int m = 32; m; m >>= 1) mx = fmaxf(mx, __shfl_xor(mx, m));
            float e = __expf(s - mx);
            float sum = e;
#pragma unroll
            for (int m = 32; m; m >>= 1) sum += __shfl_xor(sum, m);
            float p = e * (1.f / sum);
            if (j < 49) S_s[i][j] = p;
        }
        __syncthreads();

        // PV: X[i][d] = sum_j P[i][j] * v[j][d]
        for (int o = t; o < 392; o += 256) {
            int i = o >> 3, dd = (o & 7) << 2;
            float4 a4 = make_float4(0.f, 0.f, 0.f, 0.f);
#pragma unroll 7
            for (int jq = 0; jq < 49; ++jq) {
                float p = S_s[i][jq];
                float4 vf = *(const float4*)&kv_s[jq][128 + (hh << 5) + dd];
                a4.x = fmaf(p, vf.x, a4.x); a4.y = fmaf(p, vf.y, a4.y);
                a4.z = fmaf(p, vf.z, a4.z); a4.w = fmaf(p, vf.w, a4.w);
            }
            *(float4*)(out + ((size_t)win * 49 + i) * 512 + (H << 5) + dd) = a4;
        }
        __syncthreads();
    }
}

// Kernel 2: in-place out = out @ proj_w + proj_b. 32 rows/block, 16x4 fp32
// register tile/thread, GLL-staged X (unpadded: all LDS reads are wave-
// broadcast), 1-deep W register prefetch. Race-free (block owns its rows).
__global__ __launch_bounds__(256) void proj32(
    const float* __restrict__ pw, const float* __restrict__ pb,
    float* __restrict__ io) {
    __shared__ float X_s[32][512];  // 65536 B
    const int m0 = blockIdx.x << 5;
    const int t  = threadIdx.x;
    const int c4 = (t & 127) << 2;
    const int rg = t >> 7;

    // async stage 32x512 f32 (4096 float4, 16 full-wave GLL per thread)
    const float* xsrc = io + (size_t)m0 * 512;
#pragma unroll
    for (int it = 0; it < 16; ++it) {
        const int o = t + (it << 8);
        const int wb = o & ~63;
        cp16_async(xsrc + ((size_t)o << 2), &X_s[0][0] + (wb << 2));
    }
    __syncthreads();

    const float4 bias = *(const float4*)(pb + c4);
    float4 acc[16];
#pragma unroll
    for (int r = 0; r < 16; ++r) acc[r] = bias;

    const float* wp = pw + c4;
    float4 w0 = *(const float4*)(wp);
    float4 w1 = *(const float4*)(wp + 512);
    float4 w2 = *(const float4*)(wp + 1024);
    float4 w3 = *(const float4*)(wp + 1536);
    for (int k4 = 0; k4 < 127; ++k4) {
        const float* wn = wp + (((size_t)k4 + 1) << 11);
        const float4 n0 = *(const float4*)(wn);
        const float4 n1 = *(const float4*)(wn + 512);
        const float4 n2 = *(const float4*)(wn + 1024);
        const float4 n3 = *(const float4*)(wn + 1536);
#pragma unroll
        for (int r = 0; r < 16; ++r) {
            const float4 f = *(const float4*)&X_s[(rg << 4) + r][k4 << 2];
            FMA4(acc[r], f, w0, w1, w2, w3)
        }
        w0 = n0; w1 = n1; w2 = n2; w3 = n3;
    }
#pragma unroll
    for (int r = 0; r < 16; ++r) {
        const float4 f = *(const float4*)&X_s[(rg << 4) + r][127 << 2];
        FMA4(acc[r], f, w0, w1, w2, w3)
    }

#pragma unroll
    for (int r = 0; r < 16; ++r)
        *(float4*)(io + ((size_t)(m0 + (rg << 4) + r)) * 512 + c4) = acc[r];
}

// ---------------------------------------------------------------------------
extern "C" void kernel_launch(void* const* d_in, const int* in_sizes, int n_in,
                              void* d_out, int out_size, void* d_ws, size_t ws_size,
                              hipStream_t stream) {
    const float* inputs = (const float*)d_in[0];   // [1024*49, 512]
    const float* qg     = (const float*)d_in[1];   // [64*49, 512]
    const float* qkv_w  = (const float*)d_in[2];   // [512, 1024]
    const float* qkv_b  = (const float*)d_in[3];   // [1024]
    const float* btab   = (const float*)d_in[4];   // [169, 16]
    const float* proj_w = (const float*)d_in[5];   // [512, 512]
    const float* proj_b = (const float*)d_in[6];   // [512]
    float* out = (float*)d_out;                    // [1024*49, 512]
    (void)d_ws; (void)ws_size;

    attn4<<<dim3(1024, 4), 256, 0, stream>>>(inputs, qg, qkv_w, qkv_b, btab, out);
    proj32<<<50176 / 32, 256, 0, stream>>>(proj_w, proj_b, out);
}

// Round 4
// 1495.645 us; speedup vs baseline: 3.0193x; 1.4347x over previous
//
#include <hip/hip_runtime.h>

// ---------------------------------------------------------------------------
// Round 8: occupancy attack. Rounds 5/7 both pinned at Occupancy ~12% =
// 1 block/CU (LDS 74-77 KiB; limit tracks LDS, not VGPR). Shrink LDS so
// blocks co-reside and barriers/load-latency overlap across blocks:
//   attn2: 2 heads/block (was 4), LDS 53.7 KiB -> 3 blocks/CU target,
//          __launch_bounds__(256,3). Same GLL staging + wave softmax.
//   proj16: 16 rows/block, X_s 32 KiB -> 4 blocks/CU, (256,4).
// All math fp32.
// ---------------------------------------------------------------------------

typedef __attribute__((address_space(3))) void lds_void;
typedef const __attribute__((address_space(1))) void glb_void;

__device__ __forceinline__ void cp16_async(const float* g, float* lds_wave_base) {
    __builtin_amdgcn_global_load_lds((glb_void*)g, (lds_void*)lds_wave_base, 16, 0, 0);
}

// Stage a 49x32-float tile (source row stride 512 floats) into contiguous
// 32-float LDS rows. 392 float4; tail handled by a partially-active wave.
__device__ __forceinline__ void stage49x32(const float* src, float* dst, int t) {
#pragma unroll
    for (int it = 0; it < 2; ++it) {
        const int o = t + (it << 8);
        if (o < 392) {
            const int wb = o & ~63;   // wave-uniform float4 base
            cp16_async(src + (size_t)(o >> 3) * 512 + ((o & 7) << 2),
                       dst + (wb << 2));
        }
    }
}

#define FMA4(accv, f, w0, w1, w2, w3)                                          \
  accv.x = fmaf(f.x, w0.x, accv.x); accv.x = fmaf(f.y, w1.x, accv.x);          \
  accv.x = fmaf(f.z, w2.x, accv.x); accv.x = fmaf(f.w, w3.x, accv.x);          \
  accv.y = fmaf(f.x, w0.y, accv.y); accv.y = fmaf(f.y, w1.y, accv.y);          \
  accv.y = fmaf(f.z, w2.y, accv.y); accv.y = fmaf(f.w, w3.y, accv.y);          \
  accv.z = fmaf(f.x, w0.z, accv.z); accv.z = fmaf(f.y, w1.z, accv.z);          \
  accv.z = fmaf(f.z, w2.z, accv.z); accv.z = fmaf(f.w, w3.z, accv.z);          \
  accv.w = fmaf(f.x, w0.w, accv.w); accv.w = fmaf(f.y, w1.w, accv.w);          \
  accv.w = fmaf(f.z, w2.w, accv.w); accv.w = fmaf(f.w, w3.w, accv.w);

__global__ __launch_bounds__(256, 3) void attn2(
    const float* __restrict__ inp, const float* __restrict__ qg,
    const float* __restrict__ W, const float* __restrict__ b,
    const float* __restrict__ bt, float* __restrict__ out) {
    __shared__ float kv_s[56][132];     // 29568 B; c<64 k, c>=64 v; rows 49+ pad
    __shared__ float S_s[49][50];       //  9800 B; P per head
    __shared__ float inp_s[2][56][32];  // 14336 B; GLL chunks / q slices
    // total 53704 B -> 3 blocks/CU

    const int win = blockIdx.x;   // 0..1023
    const int hg  = blockIdx.y;   // head pair 0..7 (heads hg*2, hg*2+1)
    const int t   = threadIdx.x;  // 0..255
    const int c4  = t & 31;       // float4 column 0..31 (128 cols)
    const int rg  = t >> 5;       // row group 0..7 (rows rg, rg+8, ...)
    const int wv  = t >> 6;       // wave id 0..3
    const int j   = t & 63;       // lane id

    // W column base: c4<16 -> k cols, c4>=16 -> v cols (64 each for 2 heads)
    const int colbase = (c4 < 16) ? (hg * 64 + (c4 << 2))
                                  : (512 + hg * 64 + ((c4 - 16) << 2));
    const float* ip = inp + (size_t)win * 49 * 512;

    // ---- phase 1: kv tile (49x128) = inp[win] @ W[:, cols] + b -----------
    float4 acc[7];
#pragma unroll
    for (int rr = 0; rr < 7; ++rr) acc[rr] = make_float4(0.f, 0.f, 0.f, 0.f);
    const float4 bias4 = *(const float4*)(b + colbase);

    stage49x32(ip, &inp_s[0][0][0], t);   // chunk 0 (async)
    __syncthreads();

    for (int kc = 0; kc < 512; kc += 32) {
        const int cur = (kc >> 5) & 1;
        if (kc + 32 < 512)                // issue next chunk BEFORE compute
            stage49x32(ip + kc + 32, &inp_s[cur ^ 1][0][0], t);

        const float* Wp = W + ((size_t)kc << 10) + colbase;
#pragma unroll
        for (int k4 = 0; k4 < 8; ++k4) {
            const float* wr = Wp + ((size_t)(k4 << 2) << 10);
            float4 w0 = *(const float4*)(wr);
            float4 w1 = *(const float4*)(wr + 1024);
            float4 w2 = *(const float4*)(wr + 2048);
            float4 w3 = *(const float4*)(wr + 3072);
#pragma unroll
            for (int rr = 0; rr < 7; ++rr) {   // rows rg+8*rr < 56, no predicate
                float4 f = *(const float4*)&inp_s[cur][rg + (rr << 3)][k4 << 2];
                FMA4(acc[rr], f, w0, w1, w2, w3)
            }
        }
        __syncthreads();
    }

    // writeback kv tile (+bias); pad rows never read
#pragma unroll
    for (int rr = 0; rr < 7; ++rr) {
        const int r = rg + (rr << 3);
        float4 res = make_float4(acc[rr].x + bias4.x, acc[rr].y + bias4.y,
                                 acc[rr].z + bias4.z, acc[rr].w + bias4.w);
        *(float4*)&kv_s[r][c4 << 2] = res;
    }

    // stage q for head 0 (buffer 0 last read two barriers ago -> safe)
    const float* qwin = qg + (size_t)(win >> 4) * 49 * 512 + (hg << 6);
    stage49x32(qwin, &inp_s[0][0][0], t);
    __syncthreads();

    // ---- phases 2-4 per head (2 heads) ----------------------------------
    const int jj = (j < 49) ? j : 48;     // clamp pad lanes
    const int jh = jj / 7, jw = jj - jh * 7;
    const int c_j = jh * 13 + jw;

    for (int hh = 0; hh < 2; ++hh) {
        const int H  = (hg << 1) + hh;
        const int qb = hh;

        if (hh == 0)   // async prefetch head 1's q slice
            stage49x32(qwin + 32, &inp_s[1][0][0], t);

        // lane j holds k[jj][0:32] of this head in registers
        float4 kreg[8];
#pragma unroll
        for (int d4 = 0; d4 < 8; ++d4)
            kreg[d4] = *(const float4*)&kv_s[jj][(hh << 5) + (d4 << 2)];

        // each wave owns rows i = wv, wv+4, ...
        for (int i = wv; i < 49; i += 4) {
            const int ih = i / 7, iw = i - ih * 7;
            const int r_i = ih * 13 + iw + 84;
            float s = 0.f;
#pragma unroll
            for (int d4 = 0; d4 < 8; ++d4) {
                float4 qv = *(const float4*)&inp_s[qb][i][d4 << 2];  // broadcast
                s = fmaf(qv.x, kreg[d4].x, s); s = fmaf(qv.y, kreg[d4].y, s);
                s = fmaf(qv.z, kreg[d4].z, s); s = fmaf(qv.w, kreg[d4].w, s);
            }
            s = s * 0.17677669529663687f + bt[(r_i - c_j) * 16 + H];
            if (j >= 49) s = -1e30f;
            float mx = s;
#pragma unroll
            for (int m = 32; m; m >>= 1) mx = fmaxf(mx, __shfl_xor(mx, m));
            float e = __expf(s - mx);
            float sum = e;
#pragma unroll
            for (int m = 32; m; m >>= 1) sum += __shfl_xor(sum, m);
            float p = e * (1.f / sum);
            if (j < 49) S_s[i][j] = p;
        }
        __syncthreads();   // also drains the q prefetch GLL

        // PV: X[i][d] = sum_j P[i][j] * v[j][d]
        for (int o = t; o < 392; o += 256) {
            int i = o >> 3, dd = (o & 7) << 2;
            float4 a4 = make_float4(0.f, 0.f, 0.f, 0.f);
#pragma unroll 7
            for (int jq = 0; jq < 49; ++jq) {
                float p = S_s[i][jq];
                float4 vf = *(const float4*)&kv_s[jq][64 + (hh << 5) + dd];
                a4.x = fmaf(p, vf.x, a4.x); a4.y = fmaf(p, vf.y, a4.y);
                a4.z = fmaf(p, vf.z, a4.z); a4.w = fmaf(p, vf.w, a4.w);
            }
            *(float4*)(out + ((size_t)win * 49 + i) * 512 + (H << 5) + dd) = a4;
        }
        __syncthreads();
    }
}

// Kernel 2: in-place out = out @ proj_w + proj_b. 16 rows/block (X_s 32 KiB
// -> 4 blocks/CU), 8x4 fp32 register tile/thread, GLL-staged X, 1-deep W
// register prefetch. Race-free (block owns its rows).
__global__ __launch_bounds__(256, 4) void proj16(
    const float* __restrict__ pw, const float* __restrict__ pb,
    float* __restrict__ io) {
    __shared__ float X_s[16][512];  // 32768 B
    const int m0 = blockIdx.x << 4;
    const int t  = threadIdx.x;
    const int c4 = (t & 127) << 2;
    const int rg = t >> 7;          // 0..1 -> rows rg*8 .. rg*8+7 (wave-uniform)

    // async stage 16x512 f32 (2048 float4, 8 full-wave GLL per thread)
    const float* xsrc = io + (size_t)m0 * 512;
#pragma unroll
    for (int it = 0; it < 8; ++it) {
        const int o = t + (it << 8);
        const int wb = o & ~63;
        cp16_async(xsrc + ((size_t)o << 2), &X_s[0][0] + (wb << 2));
    }
    __syncthreads();

    const float4 bias = *(const float4*)(pb + c4);
    float4 acc[8];
#pragma unroll
    for (int r = 0; r < 8; ++r) acc[r] = bias;

    const float* wp = pw + c4;
    float4 w0 = *(const float4*)(wp);
    float4 w1 = *(const float4*)(wp + 512);
    float4 w2 = *(const float4*)(wp + 1024);
    float4 w3 = *(const float4*)(wp + 1536);
    for (int k4 = 0; k4 < 127; ++k4) {
        const float* wn = wp + (((size_t)k4 + 1) << 11);
        const float4 n0 = *(const float4*)(wn);
        const float4 n1 = *(const float4*)(wn + 512);
        const float4 n2 = *(const float4*)(wn + 1024);
        const float4 n3 = *(const float4*)(wn + 1536);
#pragma unroll
        for (int r = 0; r < 8; ++r) {
            const float4 f = *(const float4*)&X_s[(rg << 3) + r][k4 << 2];
            FMA4(acc[r], f, w0, w1, w2, w3)
        }
        w0 = n0; w1 = n1; w2 = n2; w3 = n3;
    }
#pragma unroll
    for (int r = 0; r < 8; ++r) {
        const float4 f = *(const float4*)&X_s[(rg << 3) + r][127 << 2];
        FMA4(acc[r], f, w0, w1, w2, w3)
    }

#pragma unroll
    for (int r = 0; r < 8; ++r)
        *(float4*)(io + ((size_t)(m0 + (rg << 3) + r)) * 512 + c4) = acc[r];
}

// ---------------------------------------------------------------------------
extern "C" void kernel_launch(void* const* d_in, const int* in_sizes, int n_in,
                              void* d_out, int out_size, void* d_ws, size_t ws_size,
                              hipStream_t stream) {
    const float* inputs = (const float*)d_in[0];   // [1024*49, 512]
    const float* qg     = (const float*)d_in[1];   // [64*49, 512]
    const float* qkv_w  = (const float*)d_in[2];   // [512, 1024]
    const float* qkv_b  = (const float*)d_in[3];   // [1024]
    const float* btab   = (const float*)d_in[4];   // [169, 16]
    const float* proj_w = (const float*)d_in[5];   // [512, 512]
    const float* proj_b = (const float*)d_in[6];   // [512]
    float* out = (float*)d_out;                    // [1024*49, 512]
    (void)d_ws; (void)ws_size;

    attn2<<<dim3(1024, 8), 256, 0, stream>>>(inputs, qg, qkv_w, qkv_b, btab, out);
    proj16<<<50176 / 16, 256, 0, stream>>>(proj_w, proj_b, out);
}